// Round 7
// baseline (147.334 us; speedup 1.0000x reference)
//
#include <hip/hip_runtime.h>
#include <stdint.h>

// set attention: N=32, L=256, D=20, H=2, Dh=20, fp32 I/O.
// Out batch b: Q from x[b], K/V from y[(b&31)*32 + (b>>5)].
// R11: LDS diet 72.7KB -> 47.7KB -> 3 blocks/CU (24 waves/CU vs 16).
//   - Q transpose in REGISTERS: Q^T = Wq^T * X^T via swapped MFMA operands
//     (A-frag(M) == B-frag(M^T), m89 layouts), then 6x ds_bpermute + packbf
//     per tile assembles qb. No per-wave LDS scratch, no extra barrier.
//   - O normalize scratch overlays sK (dead after BAR2; pad cols still 0).
//   - Everything else (phases, barriers, primitives) v10-proven verbatim.

#define NSET 32
#define SEQL 256
#define DM   20
#define NH   2
#define DH   20

typedef __attribute__((ext_vector_type(8))) short short8;
typedef __attribute__((ext_vector_type(4))) short short4v;
typedef __attribute__((ext_vector_type(4))) float f32x4;

#define MFMA32(a, b, c) __builtin_amdgcn_mfma_f32_16x16x32_bf16((a), (b), (c), 0, 0, 0)

#if __has_builtin(__builtin_amdgcn_mfma_f32_16x16x16bf16_1k)
#define MFMA16(a, b, c) __builtin_amdgcn_mfma_f32_16x16x16bf16_1k((a), (b), (c), 0, 0, 0)
#elif __has_builtin(__builtin_amdgcn_mfma_f32_16x16x16_bf16)
#define MFMA16(a, b, c) __builtin_amdgcn_mfma_f32_16x16x16_bf16((a), (b), (c), 0, 0, 0)
#else
static __device__ __forceinline__ f32x4 MFMA16(short4v a, short4v b, f32x4 c) {
    asm volatile("s_nop 1\n\tv_mfma_f32_16x16x16_bf16 %0, %1, %2, %0\n\ts_nop 7"
                 : "+v"(c) : "v"(a), "v"(b));
    return c;
}
#endif

// fp32 -> bf16 bits, round-half-up (differs from RNE only on exact ties)
__device__ __forceinline__ uint32_t bfhu(float f) {
    return (__float_as_uint(f) + 0x8000u) >> 16;
}
// two fp32 -> packed {bf16(hi),bf16(lo)}: 2 add + 1 v_perm_b32 (v8/v9/v10-proven)
__device__ __forceinline__ uint32_t packbf(float hi, float lo) {
    return __builtin_amdgcn_perm(__float_as_uint(hi) + 0x8000u,
                                 __float_as_uint(lo) + 0x8000u, 0x07060302u);
}
__device__ __forceinline__ float fexp2(float x) {
    float r;
    asm("v_exp_f32 %0, %1" : "=v"(r) : "v"(x));
    return r;
}

// predicated b128 A/B-frag load from row-major [rows][24] bf16 region
__device__ __forceinline__ short8 ldsA(const short* base, int row, int qd) {
    short8 f = {0, 0, 0, 0, 0, 0, 0, 0};
    if (qd < 3) f = *(const short8*)(base + row * 24 + qd * 8);
    return f;
}

// global fp32 row (20 floats, 16B-aligned) -> bf16 frag for k-quad qd
__device__ __forceinline__ short8 gfrag(const float* rowp, int qd) {
    short8 f = {0, 0, 0, 0, 0, 0, 0, 0};
    if (qd < 2) {
        float4 a = *(const float4*)(rowp + qd * 8);
        float4 b = *(const float4*)(rowp + qd * 8 + 4);
        f[0] = (short)bfhu(a.x); f[1] = (short)bfhu(a.y);
        f[2] = (short)bfhu(a.z); f[3] = (short)bfhu(a.w);
        f[4] = (short)bfhu(b.x); f[5] = (short)bfhu(b.y);
        f[6] = (short)bfhu(b.z); f[7] = (short)bfhu(b.w);
    } else if (qd == 2) {
        float4 a = *(const float4*)(rowp + 16);
        f[0] = (short)bfhu(a.x); f[1] = (short)bfhu(a.y);
        f[2] = (short)bfhu(a.z); f[3] = (short)bfhu(a.w);
    }
    return f;
}

// LDS layout (47,744 B total):
//   [     0, 24576)  sKb : bf16 K, [2 heads][256 rows][24]
//                          (overlay: per-wave O scratch after BAR2; f32 sOut after BAR4)
//   [ 24576, 45696)  sVtb: bf16 V^T, [2 heads][20 d][264 s]
//   [ 45696, 47744)  sL  : f32 [512] per-row softmax denom
#define SMEM_BYTES 47744

__global__ __launch_bounds__(512, 4) void set_attn_v11(
    const float* __restrict__ x, const float* __restrict__ y,
    const float* __restrict__ wq, const float* __restrict__ wk,
    const float* __restrict__ wv, const float* __restrict__ wh,
    float* __restrict__ out)
{
    __shared__ __align__(16) char smem[SMEM_BYTES];
    short* sKb  = (short*)smem;
    short* sVtb = (short*)(smem + 24576);
    float* sL   = (float*)(smem + 45696);
    float* sOut = (float*)smem;            // overlay on sKb: [256][20] f32, epilogue only

    const int tid     = threadIdx.x;
    const int lane    = tid & 63;
    const int w       = tid >> 6;          // 0..7
    const int c       = lane & 15;
    const int qd      = lane >> 4;
    const int head    = w >> 2;            // 0 or 1
    const int rowbase = (w & 3) * 64;      // this wave's 64 rows
    const int b       = blockIdx.x;
    const int bi      = b >> 5, bj = b & 31;

    short* sK  = sKb + head * (SEQL * 24);
    short* sVt = sVtb + head * (20 * 264);
    short* myO = sKb + w * (64 * 24);      // O scratch overlay, live BAR2..BAR4

    // zero pad cols 20..23 of all 512 sKb rows (K and O writes never touch them)
    *(uint2*)(sKb + tid * 24 + 20) = make_uint2(0u, 0u);

    const float QS = 0.22360679774997896f * 1.4426950408889634f;  // scale * log2(e)

    // ================= Phase 1: projections (own head, own 64 rows) ============
    short8 xf[4];
#pragma unroll
    for (int mt = 0; mt < 4; ++mt)
        xf[mt] = gfrag(x + ((size_t)b * SEQL + rowbase + mt * 16 + c) * DM, qd);

    // Qt A-frags: wqA0 lane(c,qd): WQ[k=8qd+j][h*20+c]; wqA1: col 16+c (c<4)
    short8 wqA0 = {0,0,0,0,0,0,0,0}, wqA1 = wqA0;
#pragma unroll
    for (int j = 0; j < 8; ++j) {
        int k = qd * 8 + j;
        if (k < 20) {
            wqA0[j] = (short)bfhu(wq[k * 40 + head * 20 + c]);
            if (c < 4) wqA1[j] = (short)bfhu(wq[k * 40 + head * 20 + 16 + c]);
        }
    }

    // K/V projection B-frags (v10-exact)
    short8 wkf[2], wvf[2];
#pragma unroll
    for (int dt = 0; dt < 2; ++dt) {
        int n = dt * 16 + c;
        short8 fk = {0,0,0,0,0,0,0,0}, fv = fk;
        if (n < 20) {
#pragma unroll
            for (int j = 0; j < 8; ++j) {
                int k = qd * 8 + j;
                if (k < 20) {
                    fk[j] = (short)bfhu(wk[k * 40 + head * 20 + n]);
                    fv[j] = (short)bfhu(wv[k * 40 + head * 20 + n]);
                }
            }
        }
        wkf[dt] = fk; wvf[dt] = fv;
    }

    // bpermute lane indices for qb assembly (bytes)
    const int i01 = (c + ((qd & 1) << 5)) << 2;        // qd0->c,   qd1->c+32
    const int i23 = (c + 16 + ((qd & 1) << 5)) << 2;   // qd0->c+16, qd1->c+48
    const int iB  = c << 2;                            // qd2 -> lane (c,0)

    short8 qb[4];
#pragma unroll
    for (int mt = 0; mt < 4; ++mt) {
        int rb = rowbase + mt * 16;        // local row in [0,256)
        short8 yf = gfrag(y + ((size_t)(bj * NSET + bi) * SEQL + rb + c) * DM, qd);
#pragma unroll
        for (int dt = 0; dt < 2; ++dt) {
            f32x4 z = {0.f, 0.f, 0.f, 0.f};
            f32x4 kres = MFMA32(yf, wkf[dt], z);
            f32x4 vres = MFMA32(yf, wvf[dt], z);
            int n = dt * 16 + c;
            if (n < 20) {
#pragma unroll
                for (int reg = 0; reg < 4; ++reg)
                    sK[(rb + qd * 4 + reg) * 24 + n] = (short)bfhu(kres[reg]);
                uint2 pv = make_uint2(packbf(vres[1], vres[0]),
                                      packbf(vres[3], vres[2]));
                *(uint2*)(sVt + n * 264 + rb + qd * 4) = pv;
            }
        }
        // --- Q^T projection + in-register transpose to qb[mt] ---
        {
            f32x4 z = {0.f, 0.f, 0.f, 0.f};
            f32x4 ra = MFMA32(wqA0, xf[mt], z);   // lane(c,qd): Q[c][4qd+reg]
            f32x4 rb2 = MFMA32(wqA1, xf[mt], z);  // qd==0: Q[c][16+reg], else 0
            uint32_t dwA0 = packbf(ra[1] * QS, ra[0] * QS);
            uint32_t dwA1 = packbf(ra[3] * QS, ra[2] * QS);
            uint32_t dwB0 = packbf(rb2[1] * QS, rb2[0] * QS);
            uint32_t dwB1 = packbf(rb2[3] * QS, rb2[2] * QS);
            uint32_t t0a = (uint32_t)__builtin_amdgcn_ds_bpermute(i01, (int)dwA0);
            uint32_t t1a = (uint32_t)__builtin_amdgcn_ds_bpermute(i01, (int)dwA1);
            uint32_t t0b = (uint32_t)__builtin_amdgcn_ds_bpermute(iB, (int)dwB0);
            uint32_t t1b = (uint32_t)__builtin_amdgcn_ds_bpermute(iB, (int)dwB1);
            uint32_t t2  = (uint32_t)__builtin_amdgcn_ds_bpermute(i23, (int)dwA0);
            uint32_t t3  = (uint32_t)__builtin_amdgcn_ds_bpermute(i23, (int)dwA1);
            uint32_t q0 = qd < 2 ? t0a : (qd == 2 ? t0b : 0u);
            uint32_t q1 = qd < 2 ? t1a : (qd == 2 ? t1b : 0u);
            uint32_t q2 = qd < 2 ? t2 : 0u;
            uint32_t q3 = qd < 2 ? t3 : 0u;
            short8 f;
            *(uint2*)&f = make_uint2(q0, q1);
            *(((uint2*)&f) + 1) = make_uint2(q2, q3);
            qb[mt] = f;   // lane(c,qd): Qs[row mt*16+c][d=8qd+j], bf16(bfhu)
        }
    }
    __syncthreads();   // BAR1: sK/sVt (both heads) + pads ready

    // ================= Phase 2: s0 loop (ONE head), denominators ===============
    f32x4 oacc[4][2];
#pragma unroll
    for (int mt = 0; mt < 4; ++mt)
#pragma unroll
        for (int dt = 0; dt < 2; ++dt) oacc[mt][dt] = (f32x4){0.f, 0.f, 0.f, 0.f};
    float ls0 = 0.f, ls1 = 0.f, ls2 = 0.f, ls3 = 0.f;

    for (int s0 = 0; s0 < SEQL; s0 += 32) {
        short8 kf0 = ldsA(sK, s0 + c, qd);
        short8 kf1 = ldsA(sK, s0 + 16 + c, qd);
        short4v vb[2][2];
#pragma unroll
        for (int dt = 0; dt < 2; ++dt) {
            int d = dt * 16 + c;
#pragma unroll
            for (int st = 0; st < 2; ++st) {
                uint2 u = make_uint2(0u, 0u);
                if (d < 20)
                    u = *(const uint2*)(sVt + d * 264 + s0 + st * 16 + qd * 4);
                short4v t; *(uint2*)&t = u;
                vb[st][dt] = t;
            }
        }
#pragma unroll
        for (int mt = 0; mt < 4; ++mt) {
#pragma unroll
            for (int st = 0; st < 2; ++st) {
                f32x4 z = {0.f, 0.f, 0.f, 0.f};
                f32x4 sacc = MFMA32((st == 0 ? kf0 : kf1), qb[mt], z);
                float p0, p1, p2, p3;
                {
                    float v0 = sacc[0], v1 = sacc[1], v2 = sacc[2], v3 = sacc[3];
                    p0 = (v0 != 0.f) ? fexp2(v0) : 0.f;   // zero-logit mask
                    p1 = (v1 != 0.f) ? fexp2(v1) : 0.f;
                    p2 = (v2 != 0.f) ? fexp2(v2) : 0.f;
                    p3 = (v3 != 0.f) ? fexp2(v3) : 0.f;
                }
                float lsum = (p0 + p1) + (p2 + p3);
                if (mt == 0) ls0 += lsum;
                else if (mt == 1) ls1 += lsum;
                else if (mt == 2) ls2 += lsum;
                else ls3 += lsum;
                short4v pf;
                *(uint2*)&pf = make_uint2(packbf(p1, p0), packbf(p3, p2));
                oacc[mt][0] = MFMA16(pf, vb[st][0], oacc[mt][0]);
                oacc[mt][1] = MFMA16(pf, vb[st][1], oacc[mt][1]);
            }
        }
    }

    // softmax denominators: reduce over qd groups, broadcast via sL
    ls0 += __shfl_xor(ls0, 16, 64); ls0 += __shfl_xor(ls0, 32, 64);
    ls1 += __shfl_xor(ls1, 16, 64); ls1 += __shfl_xor(ls1, 32, 64);
    ls2 += __shfl_xor(ls2, 16, 64); ls2 += __shfl_xor(ls2, 32, 64);
    ls3 += __shfl_xor(ls3, 16, 64); ls3 += __shfl_xor(ls3, 32, 64);
    float sel = ls0;
    if (qd == 1) sel = ls1;
    if (qd == 2) sel = ls2;
    if (qd == 3) sel = ls3;
    sL[w * 64 + lane] = sel;   // sL[w*64 + i] = denom of wave-local row i
    __syncthreads();           // BAR2: sL visible; ALL s0-loop reads of sK/sVt done

    // ================= Phase 3: normalize O into sK-overlay scratch ============
    short8 whf[2];
#pragma unroll
    for (int dt = 0; dt < 2; ++dt) {
        int n = dt * 16 + c;
        short8 f = {0,0,0,0,0,0,0,0};
        if (n < 20) {
#pragma unroll
            for (int j = 0; j < 8; ++j) {
                int k = qd * 8 + j;
                if (k < 20) f[j] = (short)bfhu(wh[(head * 20 + k) * 20 + n]);
            }
        }
        whf[dt] = f;
    }
#pragma unroll
    for (int mt = 0; mt < 4; ++mt) {
        float inv[4];
#pragma unroll
        for (int reg = 0; reg < 4; ++reg)
            inv[reg] = 1.f / (sL[w * 64 + mt * 16 + qd * 4 + reg] + 1e-10f);
#pragma unroll
        for (int dt = 0; dt < 2; ++dt) {
            int n = dt * 16 + c;
            if (n < 20) {
#pragma unroll
                for (int reg = 0; reg < 4; ++reg)
                    myO[(mt * 16 + qd * 4 + reg) * 24 + n] =
                        (short)bfhu(oacc[mt][dt][reg] * inv[reg]);
            }
        }
    }
    __syncthreads();   // BAR3: O writes visible before transposed read

    // ================= Phase 4: out-projection partial (own head) ==============
    f32x4 outacc[4][2];
#pragma unroll
    for (int mt = 0; mt < 4; ++mt) {
        short8 of = ldsA(myO, mt * 16 + c, qd);
        f32x4 z = {0.f, 0.f, 0.f, 0.f};
        outacc[mt][0] = MFMA32(of, whf[0], z);
        outacc[mt][1] = MFMA32(of, whf[1], z);
    }
    __syncthreads();   // BAR4: all myO reads retired -> f32 sOut overlay safe

    // ================= Phase 5: head1 writes f32 partials to sOut ==============
    if (head == 1) {
#pragma unroll
        for (int mt = 0; mt < 4; ++mt)
#pragma unroll
            for (int dt = 0; dt < 2; ++dt) {
                int n = dt * 16 + c;
                if (n < 20) {
#pragma unroll
                    for (int reg = 0; reg < 4; ++reg) {
                        int row = rowbase + mt * 16 + qd * 4 + reg;
                        sOut[row * 20 + n] = outacc[mt][dt][reg];
                    }
                }
            }
    }
    __syncthreads();   // BAR5: partials visible

    // ================= Phase 6: head0 combines + stores ========================
    if (head == 0) {
        float* ob = out + (size_t)b * (SEQL * DH);
#pragma unroll
        for (int mt = 0; mt < 4; ++mt)
#pragma unroll
            for (int dt = 0; dt < 2; ++dt) {
                int n = dt * 16 + c;
                if (n < 20) {
#pragma unroll
                    for (int reg = 0; reg < 4; ++reg) {
                        int row = rowbase + mt * 16 + qd * 4 + reg;
                        ob[row * 20 + n] = outacc[mt][dt][reg] + sOut[row * 20 + n];
                    }
                }
            }
    }
}

extern "C" void kernel_launch(void* const* d_in, const int* in_sizes, int n_in,
                              void* d_out, int out_size, void* d_ws, size_t ws_size,
                              hipStream_t stream) {
    const float* x  = (const float*)d_in[0];
    const float* y  = (const float*)d_in[1];
    const float* wq = (const float*)d_in[2];
    const float* wk = (const float*)d_in[3];
    const float* wv = (const float*)d_in[4];
    const float* wh = (const float*)d_in[5];
    float* out = (float*)d_out;

    set_attn_v11<<<dim3(NSET * NSET), dim3(512), 0, stream>>>(x, y, wq, wk, wv, wh, out);
}

// Round 8
// 146.853 us; speedup vs baseline: 1.0033x; 1.0033x over previous
//
#include <hip/hip_runtime.h>
#include <stdint.h>

// set attention: N=32, L=256, D=20, H=2, Dh=20, fp32 I/O.
// Out batch b: Q from x[b], K/V from y[(b&31)*32 + (b>>5)].
// R12: LDS = 40960 B EXACTLY -> 4 blocks/CU (32 waves/CU, HW max).
// Ladder evidence: 8/12/16/~19 waves -> 102/96/87/76.5 us, spill-free.
//   - sK [256][20] (no pad cols): frag read = 2 predicated uint2 (b64-aligned).
//   - sVt [20][256] with XOR swizzle s^=(d&7)<<2 (both sides) - no pad stride.
//   - sL removed: denominator transpose via 16 __shfl from lanes 0..15.
//   - Q^T in registers (v11-proven), O/out overlays on sK (v11-proven).

#define NSET 32
#define SEQL 256
#define DM   20
#define NH   2
#define DH   20

typedef __attribute__((ext_vector_type(8))) short short8;
typedef __attribute__((ext_vector_type(4))) short short4v;
typedef __attribute__((ext_vector_type(4))) float f32x4;

#define MFMA32(a, b, c) __builtin_amdgcn_mfma_f32_16x16x32_bf16((a), (b), (c), 0, 0, 0)

#if __has_builtin(__builtin_amdgcn_mfma_f32_16x16x16bf16_1k)
#define MFMA16(a, b, c) __builtin_amdgcn_mfma_f32_16x16x16bf16_1k((a), (b), (c), 0, 0, 0)
#elif __has_builtin(__builtin_amdgcn_mfma_f32_16x16x16_bf16)
#define MFMA16(a, b, c) __builtin_amdgcn_mfma_f32_16x16x16_bf16((a), (b), (c), 0, 0, 0)
#else
static __device__ __forceinline__ f32x4 MFMA16(short4v a, short4v b, f32x4 c) {
    asm volatile("s_nop 1\n\tv_mfma_f32_16x16x16_bf16 %0, %1, %2, %0\n\ts_nop 7"
                 : "+v"(c) : "v"(a), "v"(b));
    return c;
}
#endif

// fp32 -> bf16 bits, round-half-up (differs from RNE only on exact ties)
__device__ __forceinline__ uint32_t bfhu(float f) {
    return (__float_as_uint(f) + 0x8000u) >> 16;
}
// two fp32 -> packed {bf16(hi),bf16(lo)}: 2 add + 1 v_perm_b32 (v8..v11-proven)
__device__ __forceinline__ uint32_t packbf(float hi, float lo) {
    return __builtin_amdgcn_perm(__float_as_uint(hi) + 0x8000u,
                                 __float_as_uint(lo) + 0x8000u, 0x07060302u);
}
__device__ __forceinline__ float fexp2(float x) {
    float r;
    asm("v_exp_f32 %0, %1" : "=v"(r) : "v"(x));
    return r;
}

// predicated A/B-frag load from row-major [rows][20] bf16 region (two b64 reads)
__device__ __forceinline__ short8 ldsA20(const short* base, int row, int qd) {
    uint2 lo = make_uint2(0u, 0u), hi = make_uint2(0u, 0u);
    const short* p = base + row * 20 + qd * 8;
    if (qd < 2) { lo = *(const uint2*)p; hi = *(const uint2*)(p + 4); }
    else if (qd == 2) { lo = *(const uint2*)p; }
    short8 f;
    *(uint2*)&f = lo;
    *(((uint2*)&f) + 1) = hi;
    return f;
}

// XOR-swizzled short-index into a head's sVt [20][256]: flips s bits 2..4 by d&7
__device__ __forceinline__ int vtoff(int d, int s) {
    return d * 256 + (s ^ ((d & 7) << 2));
}

// global fp32 row (20 floats, 16B-aligned) -> bf16 frag for k-quad qd
__device__ __forceinline__ short8 gfrag(const float* rowp, int qd) {
    short8 f = {0, 0, 0, 0, 0, 0, 0, 0};
    if (qd < 2) {
        float4 a = *(const float4*)(rowp + qd * 8);
        float4 b = *(const float4*)(rowp + qd * 8 + 4);
        f[0] = (short)bfhu(a.x); f[1] = (short)bfhu(a.y);
        f[2] = (short)bfhu(a.z); f[3] = (short)bfhu(a.w);
        f[4] = (short)bfhu(b.x); f[5] = (short)bfhu(b.y);
        f[6] = (short)bfhu(b.z); f[7] = (short)bfhu(b.w);
    } else if (qd == 2) {
        float4 a = *(const float4*)(rowp + 16);
        f[0] = (short)bfhu(a.x); f[1] = (short)bfhu(a.y);
        f[2] = (short)bfhu(a.z); f[3] = (short)bfhu(a.w);
    }
    return f;
}

// LDS layout (40,960 B total = 163,840/4):
//   [     0, 20480)  sKb : bf16 K, [2 heads][256 rows][20]
//                          (overlay: per-wave O scratch after BAR2; f32 sOut after BAR4)
//   [ 20480, 40960)  sVtb: bf16 V^T, [2 heads][20 d][256 s] XOR-swizzled
#define SMEM_BYTES 40960

__global__ __launch_bounds__(512, 4) void set_attn_v12(
    const float* __restrict__ x, const float* __restrict__ y,
    const float* __restrict__ wq, const float* __restrict__ wk,
    const float* __restrict__ wv, const float* __restrict__ wh,
    float* __restrict__ out)
{
    __shared__ __align__(16) char smem[SMEM_BYTES];
    short* sKb  = (short*)smem;
    short* sVtb = (short*)(smem + 20480);
    float* sOut = (float*)smem;            // overlay on sKb: [256][20] f32, epilogue only

    const int tid     = threadIdx.x;
    const int lane    = tid & 63;
    const int w       = tid >> 6;          // 0..7
    const int c       = lane & 15;
    const int qd      = lane >> 4;
    const int head    = w >> 2;            // 0 or 1
    const int rowbase = (w & 3) * 64;      // this wave's 64 rows
    const int b       = blockIdx.x;
    const int bi      = b >> 5, bj = b & 31;

    short* sK  = sKb + head * (SEQL * 20);
    short* sVt = sVtb + head * (20 * 256);
    short* myO = sKb + w * (64 * 20);      // O scratch overlay, live BAR2..BAR4

    const float QS = 0.22360679774997896f * 1.4426950408889634f;  // scale * log2(e)

    // ================= Phase 1: projections (own head, own 64 rows) ============
    short8 xf[4];
#pragma unroll
    for (int mt = 0; mt < 4; ++mt)
        xf[mt] = gfrag(x + ((size_t)b * SEQL + rowbase + mt * 16 + c) * DM, qd);

    // Qt A-frags: wqA0 lane(c,qd): WQ[k=8qd+j][h*20+c]; wqA1: col 16+c (c<4)
    short8 wqA0 = {0,0,0,0,0,0,0,0}, wqA1 = wqA0;
#pragma unroll
    for (int j = 0; j < 8; ++j) {
        int k = qd * 8 + j;
        if (k < 20) {
            wqA0[j] = (short)bfhu(wq[k * 40 + head * 20 + c]);
            if (c < 4) wqA1[j] = (short)bfhu(wq[k * 40 + head * 20 + 16 + c]);
        }
    }

    // K/V projection B-frags
    short8 wkf[2], wvf[2];
#pragma unroll
    for (int dt = 0; dt < 2; ++dt) {
        int n = dt * 16 + c;
        short8 fk = {0,0,0,0,0,0,0,0}, fv = fk;
        if (n < 20) {
#pragma unroll
            for (int j = 0; j < 8; ++j) {
                int k = qd * 8 + j;
                if (k < 20) {
                    fk[j] = (short)bfhu(wk[k * 40 + head * 20 + n]);
                    fv[j] = (short)bfhu(wv[k * 40 + head * 20 + n]);
                }
            }
        }
        wkf[dt] = fk; wvf[dt] = fv;
    }

    // bpermute lane indices for qb assembly (bytes)
    const int i01 = (c + ((qd & 1) << 5)) << 2;        // qd0->c,   qd1->c+32
    const int i23 = (c + 16 + ((qd & 1) << 5)) << 2;   // qd0->c+16, qd1->c+48
    const int iB  = c << 2;                            // qd2 -> lane (c,0)

    short8 qb[4];
#pragma unroll
    for (int mt = 0; mt < 4; ++mt) {
        int rb = rowbase + mt * 16;        // local row in [0,256)
        short8 yf = gfrag(y + ((size_t)(bj * NSET + bi) * SEQL + rb + c) * DM, qd);
#pragma unroll
        for (int dt = 0; dt < 2; ++dt) {
            f32x4 z = {0.f, 0.f, 0.f, 0.f};
            f32x4 kres = MFMA32(yf, wkf[dt], z);
            f32x4 vres = MFMA32(yf, wvf[dt], z);
            int n = dt * 16 + c;
            if (n < 20) {
#pragma unroll
                for (int reg = 0; reg < 4; ++reg)
                    sK[(rb + qd * 4 + reg) * 20 + n] = (short)bfhu(kres[reg]);
                uint2 pv = make_uint2(packbf(vres[1], vres[0]),
                                      packbf(vres[3], vres[2]));
                *(uint2*)(sVt + vtoff(n, rb + qd * 4)) = pv;
            }
        }
        // --- Q^T projection + in-register transpose to qb[mt] (v11-proven) ---
        {
            f32x4 z = {0.f, 0.f, 0.f, 0.f};
            f32x4 ra = MFMA32(wqA0, xf[mt], z);   // lane(c,qd): Q[c][4qd+reg]
            f32x4 rb2 = MFMA32(wqA1, xf[mt], z);  // qd==0: Q[c][16+reg], else 0
            uint32_t dwA0 = packbf(ra[1] * QS, ra[0] * QS);
            uint32_t dwA1 = packbf(ra[3] * QS, ra[2] * QS);
            uint32_t dwB0 = packbf(rb2[1] * QS, rb2[0] * QS);
            uint32_t dwB1 = packbf(rb2[3] * QS, rb2[2] * QS);
            uint32_t t0a = (uint32_t)__builtin_amdgcn_ds_bpermute(i01, (int)dwA0);
            uint32_t t1a = (uint32_t)__builtin_amdgcn_ds_bpermute(i01, (int)dwA1);
            uint32_t t0b = (uint32_t)__builtin_amdgcn_ds_bpermute(iB, (int)dwB0);
            uint32_t t1b = (uint32_t)__builtin_amdgcn_ds_bpermute(iB, (int)dwB1);
            uint32_t t2  = (uint32_t)__builtin_amdgcn_ds_bpermute(i23, (int)dwA0);
            uint32_t t3  = (uint32_t)__builtin_amdgcn_ds_bpermute(i23, (int)dwA1);
            uint32_t q0 = qd < 2 ? t0a : (qd == 2 ? t0b : 0u);
            uint32_t q1 = qd < 2 ? t1a : (qd == 2 ? t1b : 0u);
            uint32_t q2 = qd < 2 ? t2 : 0u;
            uint32_t q3 = qd < 2 ? t3 : 0u;
            short8 f;
            *(uint2*)&f = make_uint2(q0, q1);
            *(((uint2*)&f) + 1) = make_uint2(q2, q3);
            qb[mt] = f;   // lane(c,qd): Qs[row mt*16+c][d=8qd+j]
        }
    }
    __syncthreads();   // BAR1: sK/sVt (both heads) ready

    // ================= Phase 2: s0 loop (ONE head), denominators ===============
    f32x4 oacc[4][2];
#pragma unroll
    for (int mt = 0; mt < 4; ++mt)
#pragma unroll
        for (int dt = 0; dt < 2; ++dt) oacc[mt][dt] = (f32x4){0.f, 0.f, 0.f, 0.f};
    float ls0 = 0.f, ls1 = 0.f, ls2 = 0.f, ls3 = 0.f;

    for (int s0 = 0; s0 < SEQL; s0 += 32) {
        short8 kf0 = ldsA20(sK, s0 + c, qd);
        short8 kf1 = ldsA20(sK, s0 + 16 + c, qd);
        short4v vb[2][2];
#pragma unroll
        for (int dt = 0; dt < 2; ++dt) {
            int d = dt * 16 + c;
#pragma unroll
            for (int st = 0; st < 2; ++st) {
                uint2 u = make_uint2(0u, 0u);
                if (d < 20)
                    u = *(const uint2*)(sVt + vtoff(d, s0 + st * 16 + qd * 4));
                short4v t; *(uint2*)&t = u;
                vb[st][dt] = t;
            }
        }
#pragma unroll
        for (int mt = 0; mt < 4; ++mt) {
#pragma unroll
            for (int st = 0; st < 2; ++st) {
                f32x4 z = {0.f, 0.f, 0.f, 0.f};
                f32x4 sacc = MFMA32((st == 0 ? kf0 : kf1), qb[mt], z);
                float p0, p1, p2, p3;
                {
                    float v0 = sacc[0], v1 = sacc[1], v2 = sacc[2], v3 = sacc[3];
                    p0 = (v0 != 0.f) ? fexp2(v0) : 0.f;   // zero-logit mask
                    p1 = (v1 != 0.f) ? fexp2(v1) : 0.f;
                    p2 = (v2 != 0.f) ? fexp2(v2) : 0.f;
                    p3 = (v3 != 0.f) ? fexp2(v3) : 0.f;
                }
                float lsum = (p0 + p1) + (p2 + p3);
                if (mt == 0) ls0 += lsum;
                else if (mt == 1) ls1 += lsum;
                else if (mt == 2) ls2 += lsum;
                else ls3 += lsum;
                short4v pf;
                *(uint2*)&pf = make_uint2(packbf(p1, p0), packbf(p3, p2));
                oacc[mt][0] = MFMA16(pf, vb[st][0], oacc[mt][0]);
                oacc[mt][1] = MFMA16(pf, vb[st][1], oacc[mt][1]);
            }
        }
    }

    // denominators: reduce over qd groups -> every lane holds full denom of
    // row mt*16+c; transpose (c -> qd*4+reg) via shfl from lanes 0..15
    ls0 += __shfl_xor(ls0, 16, 64); ls0 += __shfl_xor(ls0, 32, 64);
    ls1 += __shfl_xor(ls1, 16, 64); ls1 += __shfl_xor(ls1, 32, 64);
    ls2 += __shfl_xor(ls2, 16, 64); ls2 += __shfl_xor(ls2, 32, 64);
    ls3 += __shfl_xor(ls3, 16, 64); ls3 += __shfl_xor(ls3, 32, 64);
    __syncthreads();   // BAR2: ALL s0-loop reads of sK/sVt done -> overlay safe

    // ================= Phase 3: normalize O into sK-overlay scratch ============
    short8 whf[2];
#pragma unroll
    for (int dt = 0; dt < 2; ++dt) {
        int n = dt * 16 + c;
        short8 f = {0,0,0,0,0,0,0,0};
        if (n < 20) {
#pragma unroll
            for (int j = 0; j < 8; ++j) {
                int k = qd * 8 + j;
                if (k < 20) f[j] = (short)bfhu(wh[(head * 20 + k) * 20 + n]);
            }
        }
        whf[dt] = f;
    }
#pragma unroll
    for (int mt = 0; mt < 4; ++mt) {
        float lsm = (mt == 0) ? ls0 : (mt == 1) ? ls1 : (mt == 2) ? ls2 : ls3;
        float inv[4];
#pragma unroll
        for (int reg = 0; reg < 4; ++reg)
            inv[reg] = 1.f / (__shfl(lsm, qd * 4 + reg, 64) + 1e-10f);
#pragma unroll
        for (int dt = 0; dt < 2; ++dt) {
            int n = dt * 16 + c;
            if (n < 20) {
#pragma unroll
                for (int reg = 0; reg < 4; ++reg)
                    myO[(mt * 16 + qd * 4 + reg) * 20 + n] =
                        (short)bfhu(oacc[mt][dt][reg] * inv[reg]);
            }
        }
    }
    __syncthreads();   // BAR3: O writes visible before transposed read

    // ================= Phase 4: out-projection partial (own head) ==============
    f32x4 outacc[4][2];
#pragma unroll
    for (int mt = 0; mt < 4; ++mt) {
        short8 of = ldsA20(myO, mt * 16 + c, qd);
        f32x4 z = {0.f, 0.f, 0.f, 0.f};
        outacc[mt][0] = MFMA32(of, whf[0], z);
        outacc[mt][1] = MFMA32(of, whf[1], z);
    }
    __syncthreads();   // BAR4: all myO reads retired -> f32 sOut overlay safe

    // ================= Phase 5: head1 writes f32 partials to sOut ==============
    if (head == 1) {
#pragma unroll
        for (int mt = 0; mt < 4; ++mt)
#pragma unroll
            for (int dt = 0; dt < 2; ++dt) {
                int n = dt * 16 + c;
                if (n < 20) {
#pragma unroll
                    for (int reg = 0; reg < 4; ++reg) {
                        int row = rowbase + mt * 16 + qd * 4 + reg;
                        sOut[row * 20 + n] = outacc[mt][dt][reg];
                    }
                }
            }
    }
    __syncthreads();   // BAR5: partials visible

    // ================= Phase 6: head0 combines + stores ========================
    if (head == 0) {
        float* ob = out + (size_t)b * (SEQL * DH);
#pragma unroll
        for (int mt = 0; mt < 4; ++mt)
#pragma unroll
            for (int dt = 0; dt < 2; ++dt) {
                int n = dt * 16 + c;
                if (n < 20) {
#pragma unroll
                    for (int reg = 0; reg < 4; ++reg) {
                        int row = rowbase + mt * 16 + qd * 4 + reg;
                        ob[row * 20 + n] = outacc[mt][dt][reg] + sOut[row * 20 + n];
                    }
                }
            }
    }
}

extern "C" void kernel_launch(void* const* d_in, const int* in_sizes, int n_in,
                              void* d_out, int out_size, void* d_ws, size_t ws_size,
                              hipStream_t stream) {
    const float* x  = (const float*)d_in[0];
    const float* y  = (const float*)d_in[1];
    const float* wq = (const float*)d_in[2];
    const float* wk = (const float*)d_in[3];
    const float* wv = (const float*)d_in[4];
    const float* wh = (const float*)d_in[5];
    float* out = (float*)d_out;

    set_attn_v12<<<dim3(NSET * NSET), dim3(512), 0, stream>>>(x, y, wq, wk, wv, wh, out);
}

// Round 9
// 137.689 us; speedup vs baseline: 1.0700x; 1.0666x over previous
//
#include <hip/hip_runtime.h>
#include <stdint.h>

// set attention: N=32, L=256, D=20, H=2, Dh=20, fp32 I/O.
// Out batch b: Q from x[b], K/V from y[(b&31)*32 + (b>>5)].
// R13: VALU-count cuts on v12 (76.5us). Occupancy lever proven dead (v12 null).
//   1. Softmax denominator via MFMA ones-column: sVt row d=20 = bf16(1.0);
//      PV MFMA16 computes O[row][20] = sum_s P[row][s]. Deletes lsum adds +
//      shfl_xor reductions; normalize reads denom via one shfl from lane qd*16+4.
//   2. Weight gathers at dword granularity (packbf pairs, qd-level guards) -
//      no 16-bit element inserts.
//   3. Perm-based gfrag (v8-proven).
// Everything else (layout, swizzle, barriers, primitives) v12-proven verbatim.

#define NSET 32
#define SEQL 256
#define DM   20
#define NH   2
#define DH   20

typedef __attribute__((ext_vector_type(8))) short short8;
typedef __attribute__((ext_vector_type(4))) short short4v;
typedef __attribute__((ext_vector_type(4))) float f32x4;

#define MFMA32(a, b, c) __builtin_amdgcn_mfma_f32_16x16x32_bf16((a), (b), (c), 0, 0, 0)

#if __has_builtin(__builtin_amdgcn_mfma_f32_16x16x16bf16_1k)
#define MFMA16(a, b, c) __builtin_amdgcn_mfma_f32_16x16x16bf16_1k((a), (b), (c), 0, 0, 0)
#elif __has_builtin(__builtin_amdgcn_mfma_f32_16x16x16_bf16)
#define MFMA16(a, b, c) __builtin_amdgcn_mfma_f32_16x16x16_bf16((a), (b), (c), 0, 0, 0)
#else
static __device__ __forceinline__ f32x4 MFMA16(short4v a, short4v b, f32x4 c) {
    asm volatile("s_nop 1\n\tv_mfma_f32_16x16x16_bf16 %0, %1, %2, %0\n\ts_nop 7"
                 : "+v"(c) : "v"(a), "v"(b));
    return c;
}
#endif

// fp32 -> bf16 bits, round-half-up (differs from RNE only on exact ties)
__device__ __forceinline__ uint32_t bfhu(float f) {
    return (__float_as_uint(f) + 0x8000u) >> 16;
}
// two fp32 -> packed {bf16(hi),bf16(lo)}: 2 add + 1 v_perm_b32 (v8..v12-proven)
__device__ __forceinline__ uint32_t packbf(float hi, float lo) {
    return __builtin_amdgcn_perm(__float_as_uint(hi) + 0x8000u,
                                 __float_as_uint(lo) + 0x8000u, 0x07060302u);
}
__device__ __forceinline__ float fexp2(float x) {
    float r;
    asm("v_exp_f32 %0, %1" : "=v"(r) : "v"(x));
    return r;
}

// predicated A/B-frag load from row-major [rows][20] bf16 region (two b64 reads)
__device__ __forceinline__ short8 ldsA20(const short* base, int row, int qd) {
    uint2 lo = make_uint2(0u, 0u), hi = make_uint2(0u, 0u);
    const short* p = base + row * 20 + qd * 8;
    if (qd < 2) { lo = *(const uint2*)p; hi = *(const uint2*)(p + 4); }
    else if (qd == 2) { lo = *(const uint2*)p; }
    short8 f;
    *(uint2*)&f = lo;
    *(((uint2*)&f) + 1) = hi;
    return f;
}

// XOR-swizzled short-index into a head's sVt [21][256]: flips s bits 2..4 by d&7
__device__ __forceinline__ int vtoff(int d, int s) {
    return d * 256 + (s ^ ((d & 7) << 2));
}

// global fp32 row (20 floats, 16B-aligned) -> bf16 frag for k-quad qd (v8-proven)
__device__ __forceinline__ short8 gfrag(const float* rowp, int qd) {
    short8 f = {0, 0, 0, 0, 0, 0, 0, 0};
    if (qd < 2) {
        float4 a = *(const float4*)(rowp + qd * 8);
        float4 b = *(const float4*)(rowp + qd * 8 + 4);
        *(uint2*)&f = make_uint2(packbf(a.y, a.x), packbf(a.w, a.z));
        *(((uint2*)&f) + 1) = make_uint2(packbf(b.y, b.x), packbf(b.w, b.z));
    } else if (qd == 2) {
        float4 a = *(const float4*)(rowp + 16);
        *(uint2*)&f = make_uint2(packbf(a.y, a.x), packbf(a.w, a.z));
    }
    return f;
}

// weight B/A-frag gather, stride 40 floats (WQ/WK/WV: [20][40]).
// colp = &W[0][col]; rows k = qd*8 .. qd*8+7; valid k<20. Dword-granular.
__device__ __forceinline__ short8 gatherW40(const float* colp, int qd, bool act) {
    uint32_t u0 = 0u, u1 = 0u, u2 = 0u, u3 = 0u;
    if (act && qd < 3) {
        const float* p = colp + qd * 8 * 40;
        u0 = packbf(p[40], p[0]);        // k = qd*8, qd*8+1
        u1 = packbf(p[120], p[80]);      // k = qd*8+2, +3
        if (qd < 2) {
            u2 = packbf(p[200], p[160]); // +4, +5
            u3 = packbf(p[280], p[240]); // +6, +7
        }
    }
    short8 f;
    *(uint2*)&f = make_uint2(u0, u1);
    *(((uint2*)&f) + 1) = make_uint2(u2, u3);
    return f;
}

// same, stride 20 floats (WH: [40][20]); colp = &WH[head*20][col]
__device__ __forceinline__ short8 gatherW20(const float* colp, int qd, bool act) {
    uint32_t u0 = 0u, u1 = 0u, u2 = 0u, u3 = 0u;
    if (act && qd < 3) {
        const float* p = colp + qd * 8 * 20;
        u0 = packbf(p[20], p[0]);
        u1 = packbf(p[60], p[40]);
        if (qd < 2) {
            u2 = packbf(p[100], p[80]);
            u3 = packbf(p[140], p[120]);
        }
    }
    short8 f;
    *(uint2*)&f = make_uint2(u0, u1);
    *(((uint2*)&f) + 1) = make_uint2(u2, u3);
    return f;
}

// LDS layout (41,984 B total):
//   [     0, 20480)  sKb : bf16 K, [2 heads][256 rows][20]
//                          (overlay: per-wave O scratch after BAR2; f32 sOut after BAR4)
//   [ 20480, 41984)  sVtb: bf16 V^T, [2 heads][21 d][256 s] XOR-swizzled
//                          (d=20 row = 1.0 -> MFMA computes softmax denominator)
#define SMEM_BYTES 41984

__global__ __launch_bounds__(512, 4) void set_attn_v13(
    const float* __restrict__ x, const float* __restrict__ y,
    const float* __restrict__ wq, const float* __restrict__ wk,
    const float* __restrict__ wv, const float* __restrict__ wh,
    float* __restrict__ out)
{
    __shared__ __align__(16) char smem[SMEM_BYTES];
    short* sKb  = (short*)smem;
    short* sVtb = (short*)(smem + 20480);
    float* sOut = (float*)smem;            // overlay on sKb: [256][20] f32, epilogue only

    const int tid     = threadIdx.x;
    const int lane    = tid & 63;
    const int w       = tid >> 6;          // 0..7
    const int c       = lane & 15;
    const int qd      = lane >> 4;
    const int head    = w >> 2;            // 0 or 1
    const int rowbase = (w & 3) * 64;      // this wave's 64 rows
    const int b       = blockIdx.x;
    const int bi      = b >> 5, bj = b & 31;

    short* sK  = sKb + head * (SEQL * 20);
    short* sVt = sVtb + head * (21 * 256);
    short* myO = sKb + w * (64 * 20);      // O scratch overlay, live BAR2..BAR4

    // ones-row d=20 (denominator column); each wave covers its 64 s values
    sVt[vtoff(20, rowbase + lane)] = (short)0x3F80;

    const float QS = 0.22360679774997896f * 1.4426950408889634f;  // scale * log2(e)

    // ================= Phase 1: projections (own head, own 64 rows) ============
    short8 xf[4];
#pragma unroll
    for (int mt = 0; mt < 4; ++mt)
        xf[mt] = gfrag(x + ((size_t)b * SEQL + rowbase + mt * 16 + c) * DM, qd);

    // Qt A-frags: wqA0 lane(c,qd): WQ[k=8qd+j][h*20+c]; wqA1: col 16+c (c<4)
    short8 wqA0 = gatherW40(wq + head * 20 + c, qd, true);
    short8 wqA1 = gatherW40(wq + head * 20 + 16 + c, qd, c < 4);

    // K/V projection B-frags
    short8 wkf[2], wvf[2];
#pragma unroll
    for (int dt = 0; dt < 2; ++dt) {
        int n = dt * 16 + c;
        wkf[dt] = gatherW40(wk + head * 20 + n, qd, n < 20);
        wvf[dt] = gatherW40(wv + head * 20 + n, qd, n < 20);
    }

    // bpermute lane indices for qb assembly (bytes)
    const int i01 = (c + ((qd & 1) << 5)) << 2;        // qd0->c,   qd1->c+32
    const int i23 = (c + 16 + ((qd & 1) << 5)) << 2;   // qd0->c+16, qd1->c+48
    const int iB  = c << 2;                            // qd2 -> lane (c,0)

    short8 qb[4];
#pragma unroll
    for (int mt = 0; mt < 4; ++mt) {
        int rb = rowbase + mt * 16;        // local row in [0,256)
        short8 yf = gfrag(y + ((size_t)(bj * NSET + bi) * SEQL + rb + c) * DM, qd);
#pragma unroll
        for (int dt = 0; dt < 2; ++dt) {
            f32x4 z = {0.f, 0.f, 0.f, 0.f};
            f32x4 kres = MFMA32(yf, wkf[dt], z);
            f32x4 vres = MFMA32(yf, wvf[dt], z);
            int n = dt * 16 + c;
            if (n < 20) {
#pragma unroll
                for (int reg = 0; reg < 4; ++reg)
                    sK[(rb + qd * 4 + reg) * 20 + n] = (short)bfhu(kres[reg]);
                uint2 pv = make_uint2(packbf(vres[1], vres[0]),
                                      packbf(vres[3], vres[2]));
                *(uint2*)(sVt + vtoff(n, rb + qd * 4)) = pv;
            }
        }
        // --- Q^T projection + in-register transpose to qb[mt] (v11-proven) ---
        {
            f32x4 z = {0.f, 0.f, 0.f, 0.f};
            f32x4 ra = MFMA32(wqA0, xf[mt], z);   // lane(c,qd): Q[c][4qd+reg]
            f32x4 rb2 = MFMA32(wqA1, xf[mt], z);  // qd==0: Q[c][16+reg], else 0
            uint32_t dwA0 = packbf(ra[1] * QS, ra[0] * QS);
            uint32_t dwA1 = packbf(ra[3] * QS, ra[2] * QS);
            uint32_t dwB0 = packbf(rb2[1] * QS, rb2[0] * QS);
            uint32_t dwB1 = packbf(rb2[3] * QS, rb2[2] * QS);
            uint32_t t0a = (uint32_t)__builtin_amdgcn_ds_bpermute(i01, (int)dwA0);
            uint32_t t1a = (uint32_t)__builtin_amdgcn_ds_bpermute(i01, (int)dwA1);
            uint32_t t0b = (uint32_t)__builtin_amdgcn_ds_bpermute(iB, (int)dwB0);
            uint32_t t1b = (uint32_t)__builtin_amdgcn_ds_bpermute(iB, (int)dwB1);
            uint32_t t2  = (uint32_t)__builtin_amdgcn_ds_bpermute(i23, (int)dwA0);
            uint32_t t3  = (uint32_t)__builtin_amdgcn_ds_bpermute(i23, (int)dwA1);
            uint32_t q0 = qd < 2 ? t0a : (qd == 2 ? t0b : 0u);
            uint32_t q1 = qd < 2 ? t1a : (qd == 2 ? t1b : 0u);
            uint32_t q2 = qd < 2 ? t2 : 0u;
            uint32_t q3 = qd < 2 ? t3 : 0u;
            short8 f;
            *(uint2*)&f = make_uint2(q0, q1);
            *(((uint2*)&f) + 1) = make_uint2(q2, q3);
            qb[mt] = f;   // lane(c,qd): Qs[row mt*16+c][d=8qd+j]
        }
    }
    __syncthreads();   // BAR1: sK/sVt (both heads, incl. ones-row) ready

    // ================= Phase 2: s0 loop (ONE head) =============================
    f32x4 oacc[4][2];
#pragma unroll
    for (int mt = 0; mt < 4; ++mt)
#pragma unroll
        for (int dt = 0; dt < 2; ++dt) oacc[mt][dt] = (f32x4){0.f, 0.f, 0.f, 0.f};

    for (int s0 = 0; s0 < SEQL; s0 += 32) {
        short8 kf0 = ldsA20(sK, s0 + c, qd);
        short8 kf1 = ldsA20(sK, s0 + 16 + c, qd);
        short4v vb[2][2];
#pragma unroll
        for (int dt = 0; dt < 2; ++dt) {
            int d = dt * 16 + c;
#pragma unroll
            for (int st = 0; st < 2; ++st) {
                uint2 u = make_uint2(0u, 0u);
                if (d < 21)   // d==20 loads the ones-row -> denom column
                    u = *(const uint2*)(sVt + vtoff(d, s0 + st * 16 + qd * 4));
                short4v t; *(uint2*)&t = u;
                vb[st][dt] = t;
            }
        }
#pragma unroll
        for (int mt = 0; mt < 4; ++mt) {
#pragma unroll
            for (int st = 0; st < 2; ++st) {
                f32x4 z = {0.f, 0.f, 0.f, 0.f};
                f32x4 sacc = MFMA32((st == 0 ? kf0 : kf1), qb[mt], z);
                float p0, p1, p2, p3;
                {
                    float v0 = sacc[0], v1 = sacc[1], v2 = sacc[2], v3 = sacc[3];
                    p0 = (v0 != 0.f) ? fexp2(v0) : 0.f;   // zero-logit mask
                    p1 = (v1 != 0.f) ? fexp2(v1) : 0.f;
                    p2 = (v2 != 0.f) ? fexp2(v2) : 0.f;
                    p3 = (v3 != 0.f) ? fexp2(v3) : 0.f;
                }
                short4v pf;
                *(uint2*)&pf = make_uint2(packbf(p1, p0), packbf(p3, p2));
                oacc[mt][0] = MFMA16(pf, vb[st][0], oacc[mt][0]);
                oacc[mt][1] = MFMA16(pf, vb[st][1], oacc[mt][1]);
            }
        }
    }
    __syncthreads();   // BAR2: ALL s0-loop reads of sK/sVt done -> overlay safe

    // ================= Phase 3: normalize O into sK-overlay scratch ============
    // denominator of row mt*16+qd*4+reg = oacc[mt][1][reg] at lane qd*16+4 (d=20)
    short8 whf[2];
#pragma unroll
    for (int dt = 0; dt < 2; ++dt) {
        int n = dt * 16 + c;
        whf[dt] = gatherW20(wh + head * 20 * 20 + n, qd, n < 20);
    }
    const int dsrc = (lane & 48) + 4;   // lane qd*16+4 of own qd group
#pragma unroll
    for (int mt = 0; mt < 4; ++mt) {
        float inv[4];
#pragma unroll
        for (int reg = 0; reg < 4; ++reg)
            inv[reg] = 1.f / (__shfl(oacc[mt][1][reg], dsrc, 64) + 1e-10f);
#pragma unroll
        for (int dt = 0; dt < 2; ++dt) {
            int n = dt * 16 + c;
            if (n < 20) {
#pragma unroll
                for (int reg = 0; reg < 4; ++reg)
                    myO[(mt * 16 + qd * 4 + reg) * 20 + n] =
                        (short)bfhu(oacc[mt][dt][reg] * inv[reg]);
            }
        }
    }
    __syncthreads();   // BAR3: O writes visible before transposed read

    // ================= Phase 4: out-projection partial (own head) ==============
    f32x4 outacc[4][2];
#pragma unroll
    for (int mt = 0; mt < 4; ++mt) {
        short8 of = ldsA20(myO, mt * 16 + c, qd);
        f32x4 z = {0.f, 0.f, 0.f, 0.f};
        outacc[mt][0] = MFMA32(of, whf[0], z);
        outacc[mt][1] = MFMA32(of, whf[1], z);
    }
    __syncthreads();   // BAR4: all myO reads retired -> f32 sOut overlay safe

    // ================= Phase 5: head1 writes f32 partials to sOut ==============
    if (head == 1) {
#pragma unroll
        for (int mt = 0; mt < 4; ++mt)
#pragma unroll
            for (int dt = 0; dt < 2; ++dt) {
                int n = dt * 16 + c;
                if (n < 20) {
#pragma unroll
                    for (int reg = 0; reg < 4; ++reg) {
                        int row = rowbase + mt * 16 + qd * 4 + reg;
                        sOut[row * 20 + n] = outacc[mt][dt][reg];
                    }
                }
            }
    }
    __syncthreads();   // BAR5: partials visible

    // ================= Phase 6: head0 combines + stores ========================
    if (head == 0) {
        float* ob = out + (size_t)b * (SEQL * DH);
#pragma unroll
        for (int mt = 0; mt < 4; ++mt)
#pragma unroll
            for (int dt = 0; dt < 2; ++dt) {
                int n = dt * 16 + c;
                if (n < 20) {
#pragma unroll
                    for (int reg = 0; reg < 4; ++reg) {
                        int row = rowbase + mt * 16 + qd * 4 + reg;
                        ob[row * 20 + n] = outacc[mt][dt][reg] + sOut[row * 20 + n];
                    }
                }
            }
    }
}

extern "C" void kernel_launch(void* const* d_in, const int* in_sizes, int n_in,
                              void* d_out, int out_size, void* d_ws, size_t ws_size,
                              hipStream_t stream) {
    const float* x  = (const float*)d_in[0];
    const float* y  = (const float*)d_in[1];
    const float* wq = (const float*)d_in[2];
    const float* wk = (const float*)d_in[3];
    const float* wv = (const float*)d_in[4];
    const float* wh = (const float*)d_in[5];
    float* out = (float*)d_out;

    set_attn_v13<<<dim3(NSET * NSET), dim3(512), 0, stream>>>(x, y, wq, wk, wv, wh, out);
}

// Round 12
// 128.551 us; speedup vs baseline: 1.1461x; 1.0711x over previous
//
#include <hip/hip_runtime.h>
#include <stdint.h>

// set attention: N=32, L=256, D=20, H=2, Dh=20, fp32 I/O.
// Out batch b: Q from x[b], K/V from y[(b&31)*32 + (b>>5)].
// R16: exp2 via COMPILER-KNOWN builtin + zero-mask drop.
//   Evidence chain: v14/v15 NaN'd on mask-drop, but mask semantics cannot
//   produce NaN from finite values -> codegen artifact. Suspect: inline-asm
//   v_exp_f32 is TRANS; compiler can't see it, so it only worked when the
//   mask's cmp/cndmask accidentally spaced the hazard. Fix: use
//   __builtin_amdgcn_exp2f (compiler inserts hazard spacing itself).
//   Fallback if builtin missing: v13's exact masked inline-asm form (safe).
// Everything else v13-proven verbatim (65.5us, absmax 0.03125).

#define NSET 32
#define SEQL 256
#define DM   20
#define NH   2
#define DH   20

typedef __attribute__((ext_vector_type(8))) short short8;
typedef __attribute__((ext_vector_type(4))) short short4v;
typedef __attribute__((ext_vector_type(4))) float f32x4;

#define MFMA32(a, b, c) __builtin_amdgcn_mfma_f32_16x16x32_bf16((a), (b), (c), 0, 0, 0)

#if __has_builtin(__builtin_amdgcn_mfma_f32_16x16x16bf16_1k)
#define MFMA16(a, b, c) __builtin_amdgcn_mfma_f32_16x16x16bf16_1k((a), (b), (c), 0, 0, 0)
#elif __has_builtin(__builtin_amdgcn_mfma_f32_16x16x16_bf16)
#define MFMA16(a, b, c) __builtin_amdgcn_mfma_f32_16x16x16_bf16((a), (b), (c), 0, 0, 0)
#else
static __device__ __forceinline__ f32x4 MFMA16(short4v a, short4v b, f32x4 c) {
    asm volatile("s_nop 1\n\tv_mfma_f32_16x16x16_bf16 %0, %1, %2, %0\n\ts_nop 7"
                 : "+v"(c) : "v"(a), "v"(b));
    return c;
}
#endif

#if __has_builtin(__builtin_amdgcn_exp2f)
#define EXP_BUILTIN 1
__device__ __forceinline__ float fexp2(float x) { return __builtin_amdgcn_exp2f(x); }
#else
#define EXP_BUILTIN 0
__device__ __forceinline__ float fexp2(float x) {
    float r;
    asm("v_exp_f32 %0, %1" : "=v"(r) : "v"(x));
    return r;
}
#endif

// fp32 -> bf16 bits, round-half-up (differs from RNE only on exact ties)
__device__ __forceinline__ uint32_t bfhu(float f) {
    return (__float_as_uint(f) + 0x8000u) >> 16;
}
// two fp32 -> packed {bf16(hi),bf16(lo)} with round-half-up: 2 add + 1 perm
__device__ __forceinline__ uint32_t packbf(float hi, float lo) {
    return __builtin_amdgcn_perm(__float_as_uint(hi) + 0x8000u,
                                 __float_as_uint(lo) + 0x8000u, 0x07060302u);
}

// predicated A/B-frag load from row-major [rows][20] bf16 region (two b64 reads)
__device__ __forceinline__ short8 ldsA20(const short* base, int row, int qd) {
    uint2 lo = make_uint2(0u, 0u), hi = make_uint2(0u, 0u);
    const short* p = base + row * 20 + qd * 8;
    if (qd < 2) { lo = *(const uint2*)p; hi = *(const uint2*)(p + 4); }
    else if (qd == 2) { lo = *(const uint2*)p; }
    short8 f;
    *(uint2*)&f = lo;
    *(((uint2*)&f) + 1) = hi;
    return f;
}

// XOR-swizzled short-index into a head's sVt [21][256]: flips s bits 2..4 by d&7
__device__ __forceinline__ int vtoff(int d, int s) {
    return d * 256 + (s ^ ((d & 7) << 2));
}

// global fp32 row (20 floats, 16B-aligned) -> bf16 frag for k-quad qd (v8-proven)
__device__ __forceinline__ short8 gfrag(const float* rowp, int qd) {
    short8 f = {0, 0, 0, 0, 0, 0, 0, 0};
    if (qd < 2) {
        float4 a = *(const float4*)(rowp + qd * 8);
        float4 b = *(const float4*)(rowp + qd * 8 + 4);
        *(uint2*)&f = make_uint2(packbf(a.y, a.x), packbf(a.w, a.z));
        *(((uint2*)&f) + 1) = make_uint2(packbf(b.y, b.x), packbf(b.w, b.z));
    } else if (qd == 2) {
        float4 a = *(const float4*)(rowp + 16);
        *(uint2*)&f = make_uint2(packbf(a.y, a.x), packbf(a.w, a.z));
    }
    return f;
}

// weight B/A-frag gather, stride 40 floats (WQ/WK/WV: [20][40]).
__device__ __forceinline__ short8 gatherW40(const float* colp, int qd, bool act) {
    uint32_t u0 = 0u, u1 = 0u, u2 = 0u, u3 = 0u;
    if (act && qd < 3) {
        const float* p = colp + qd * 8 * 40;
        u0 = packbf(p[40], p[0]);
        u1 = packbf(p[120], p[80]);
        if (qd < 2) {
            u2 = packbf(p[200], p[160]);
            u3 = packbf(p[280], p[240]);
        }
    }
    short8 f;
    *(uint2*)&f = make_uint2(u0, u1);
    *(((uint2*)&f) + 1) = make_uint2(u2, u3);
    return f;
}

// same, stride 20 floats (WH: [40][20])
__device__ __forceinline__ short8 gatherW20(const float* colp, int qd, bool act) {
    uint32_t u0 = 0u, u1 = 0u, u2 = 0u, u3 = 0u;
    if (act && qd < 3) {
        const float* p = colp + qd * 8 * 20;
        u0 = packbf(p[20], p[0]);
        u1 = packbf(p[60], p[40]);
        if (qd < 2) {
            u2 = packbf(p[100], p[80]);
            u3 = packbf(p[140], p[120]);
        }
    }
    short8 f;
    *(uint2*)&f = make_uint2(u0, u1);
    *(((uint2*)&f) + 1) = make_uint2(u2, u3);
    return f;
}

// LDS layout (41,984 B total):
//   [     0, 20480)  sKb : bf16 K, [2 heads][256 rows][20]
//                          (overlay: per-wave O scratch after BAR2; f32 sOut after BAR4)
//   [ 20480, 41984)  sVtb: bf16 V^T, [2 heads][21 d][256 s] XOR-swizzled
//                          (d=20 row = 1.0 -> MFMA computes softmax denominator)
#define SMEM_BYTES 41984

__global__ __launch_bounds__(512, 4) void set_attn_v16(
    const float* __restrict__ x, const float* __restrict__ y,
    const float* __restrict__ wq, const float* __restrict__ wk,
    const float* __restrict__ wv, const float* __restrict__ wh,
    float* __restrict__ out)
{
    __shared__ __align__(16) char smem[SMEM_BYTES];
    short* sKb  = (short*)smem;
    short* sVtb = (short*)(smem + 20480);
    float* sOut = (float*)smem;            // overlay on sKb: [256][20] f32, epilogue only

    const int tid     = threadIdx.x;
    const int lane    = tid & 63;
    const int w       = tid >> 6;          // 0..7
    const int c       = lane & 15;
    const int qd      = lane >> 4;
    const int head    = w >> 2;            // 0 or 1
    const int rowbase = (w & 3) * 64;      // this wave's 64 rows
    const int b       = blockIdx.x;
    const int bi      = b >> 5, bj = b & 31;

    short* sK  = sKb + head * (SEQL * 20);
    short* sVt = sVtb + head * (21 * 256);
    short* myO = sKb + w * (64 * 20);      // O scratch overlay, live BAR2..BAR4

    // ones-row d=20 (denominator column); each wave covers its 64 s values
    sVt[vtoff(20, rowbase + lane)] = (short)0x3F80;

    const float QS = 0.22360679774997896f * 1.4426950408889634f;  // scale * log2(e)

    // ================= Phase 1: projections (own head, own 64 rows) ============
    short8 xf[4];
#pragma unroll
    for (int mt = 0; mt < 4; ++mt)
        xf[mt] = gfrag(x + ((size_t)b * SEQL + rowbase + mt * 16 + c) * DM, qd);

    // Qt A-frags: wqA0 lane(c,qd): WQ[k=8qd+j][h*20+c]; wqA1: col 16+c (c<4)
    short8 wqA0 = gatherW40(wq + head * 20 + c, qd, true);
    short8 wqA1 = gatherW40(wq + head * 20 + 16 + c, qd, c < 4);

    // K/V projection B-frags
    short8 wkf[2], wvf[2];
#pragma unroll
    for (int dt = 0; dt < 2; ++dt) {
        int n = dt * 16 + c;
        wkf[dt] = gatherW40(wk + head * 20 + n, qd, n < 20);
        wvf[dt] = gatherW40(wv + head * 20 + n, qd, n < 20);
    }

    // bpermute lane indices for qb assembly (bytes)
    const int i01 = (c + ((qd & 1) << 5)) << 2;        // qd0->c,   qd1->c+32
    const int i23 = (c + 16 + ((qd & 1) << 5)) << 2;   // qd0->c+16, qd1->c+48
    const int iB  = c << 2;                            // qd2 -> lane (c,0)

    short8 qb[4];
#pragma unroll
    for (int mt = 0; mt < 4; ++mt) {
        int rb = rowbase + mt * 16;        // local row in [0,256)
        short8 yf = gfrag(y + ((size_t)(bj * NSET + bi) * SEQL + rb + c) * DM, qd);
#pragma unroll
        for (int dt = 0; dt < 2; ++dt) {
            f32x4 z = {0.f, 0.f, 0.f, 0.f};
            f32x4 kres = MFMA32(yf, wkf[dt], z);
            f32x4 vres = MFMA32(yf, wvf[dt], z);
            int n = dt * 16 + c;
            if (n < 20) {
#pragma unroll
                for (int reg = 0; reg < 4; ++reg)
                    sK[(rb + qd * 4 + reg) * 20 + n] = (short)bfhu(kres[reg]);
                uint2 pv = make_uint2(packbf(vres[1], vres[0]),
                                      packbf(vres[3], vres[2]));
                *(uint2*)(sVt + vtoff(n, rb + qd * 4)) = pv;
            }
        }
        // --- Q^T projection + in-register transpose to qb[mt] (v11-proven) ---
        {
            f32x4 z = {0.f, 0.f, 0.f, 0.f};
            f32x4 ra = MFMA32(wqA0, xf[mt], z);   // lane(c,qd): Q[c][4qd+reg]
            f32x4 rb2 = MFMA32(wqA1, xf[mt], z);  // qd==0: Q[c][16+reg], else 0
            uint32_t dwA0 = packbf(ra[1] * QS, ra[0] * QS);
            uint32_t dwA1 = packbf(ra[3] * QS, ra[2] * QS);
            uint32_t dwB0 = packbf(rb2[1] * QS, rb2[0] * QS);
            uint32_t dwB1 = packbf(rb2[3] * QS, rb2[2] * QS);
            uint32_t t0a = (uint32_t)__builtin_amdgcn_ds_bpermute(i01, (int)dwA0);
            uint32_t t1a = (uint32_t)__builtin_amdgcn_ds_bpermute(i01, (int)dwA1);
            uint32_t t0b = (uint32_t)__builtin_amdgcn_ds_bpermute(iB, (int)dwB0);
            uint32_t t1b = (uint32_t)__builtin_amdgcn_ds_bpermute(iB, (int)dwB1);
            uint32_t t2  = (uint32_t)__builtin_amdgcn_ds_bpermute(i23, (int)dwA0);
            uint32_t t3  = (uint32_t)__builtin_amdgcn_ds_bpermute(i23, (int)dwA1);
            uint32_t q0 = qd < 2 ? t0a : (qd == 2 ? t0b : 0u);
            uint32_t q1 = qd < 2 ? t1a : (qd == 2 ? t1b : 0u);
            uint32_t q2 = qd < 2 ? t2 : 0u;
            uint32_t q3 = qd < 2 ? t3 : 0u;
            short8 f;
            *(uint2*)&f = make_uint2(q0, q1);
            *(((uint2*)&f) + 1) = make_uint2(q2, q3);
            qb[mt] = f;   // lane(c,qd): Qs[row mt*16+c][d=8qd+j]
        }
    }
    __syncthreads();   // BAR1: sK/sVt (both heads, incl. ones-row) ready

    // ================= Phase 2: s0 loop (ONE head) =============================
    f32x4 oacc[4][2];
#pragma unroll
    for (int mt = 0; mt < 4; ++mt)
#pragma unroll
        for (int dt = 0; dt < 2; ++dt) oacc[mt][dt] = (f32x4){0.f, 0.f, 0.f, 0.f};

    for (int s0 = 0; s0 < SEQL; s0 += 32) {
        short8 kf0 = ldsA20(sK, s0 + c, qd);
        short8 kf1 = ldsA20(sK, s0 + 16 + c, qd);
        short4v vb[2][2];
#pragma unroll
        for (int dt = 0; dt < 2; ++dt) {
            int d = dt * 16 + c;
#pragma unroll
            for (int st = 0; st < 2; ++st) {
                uint2 u = make_uint2(0u, 0u);
                if (d < 21)   // d==20 loads the ones-row -> denom column
                    u = *(const uint2*)(sVt + vtoff(d, s0 + st * 16 + qd * 4));
                short4v t; *(uint2*)&t = u;
                vb[st][dt] = t;
            }
        }
#pragma unroll
        for (int mt = 0; mt < 4; ++mt) {
#pragma unroll
            for (int st = 0; st < 2; ++st) {
                f32x4 z = {0.f, 0.f, 0.f, 0.f};
                f32x4 sacc = MFMA32((st == 0 ? kf0 : kf1), qb[mt], z);
#if EXP_BUILTIN
                // mask dropped: exp2 via compiler-known TRANS builtin
                float p0 = fexp2(sacc[0]);
                float p1 = fexp2(sacc[1]);
                float p2 = fexp2(sacc[2]);
                float p3 = fexp2(sacc[3]);
#else
                // fallback: v13's exact masked inline-asm form (hazard-spaced)
                float p0 = (sacc[0] != 0.f) ? fexp2(sacc[0]) : 0.f;
                float p1 = (sacc[1] != 0.f) ? fexp2(sacc[1]) : 0.f;
                float p2 = (sacc[2] != 0.f) ? fexp2(sacc[2]) : 0.f;
                float p3 = (sacc[3] != 0.f) ? fexp2(sacc[3]) : 0.f;
#endif
                short4v pf;
                *(uint2*)&pf = make_uint2(packbf(p1, p0), packbf(p3, p2));
                oacc[mt][0] = MFMA16(pf, vb[st][0], oacc[mt][0]);
                oacc[mt][1] = MFMA16(pf, vb[st][1], oacc[mt][1]);
            }
        }
    }
    __syncthreads();   // BAR2: ALL s0-loop reads of sK/sVt done -> overlay safe

    // ================= Phase 3: normalize O into sK-overlay scratch ============
    // denominator of row mt*16+qd*4+reg = oacc[mt][1][reg] at lane qd*16+4 (d=20)
    short8 whf[2];
#pragma unroll
    for (int dt = 0; dt < 2; ++dt) {
        int n = dt * 16 + c;
        whf[dt] = gatherW20(wh + head * 20 * 20 + n, qd, n < 20);
    }
    const int dsrc = (lane & 48) + 4;   // lane qd*16+4 of own qd group
#pragma unroll
    for (int mt = 0; mt < 4; ++mt) {
        float inv[4];
#pragma unroll
        for (int reg = 0; reg < 4; ++reg)
            inv[reg] = 1.f / (__shfl(oacc[mt][1][reg], dsrc, 64) + 1e-10f);
#pragma unroll
        for (int dt = 0; dt < 2; ++dt) {
            int n = dt * 16 + c;
            if (n < 20) {
#pragma unroll
                for (int reg = 0; reg < 4; ++reg)
                    myO[(mt * 16 + qd * 4 + reg) * 20 + n] =
                        (short)bfhu(oacc[mt][dt][reg] * inv[reg]);
            }
        }
    }
    __syncthreads();   // BAR3: O writes visible before transposed read

    // ================= Phase 4: out-projection partial (own head) ==============
    f32x4 outacc[4][2];
#pragma unroll
    for (int mt = 0; mt < 4; ++mt) {
        short8 of = ldsA20(myO, mt * 16 + c, qd);
        f32x4 z = {0.f, 0.f, 0.f, 0.f};
        outacc[mt][0] = MFMA32(of, whf[0], z);
        outacc[mt][1] = MFMA32(of, whf[1], z);
    }
    __syncthreads();   // BAR4: all myO reads retired -> f32 sOut overlay safe

    // ================= Phase 5: head1 writes f32 partials to sOut ==============
    if (head == 1) {
#pragma unroll
        for (int mt = 0; mt < 4; ++mt)
#pragma unroll
            for (int dt = 0; dt < 2; ++dt) {
                int n = dt * 16 + c;
                if (n < 20) {
#pragma unroll
                    for (int reg = 0; reg < 4; ++reg) {
                        int row = rowbase + mt * 16 + qd * 4 + reg;
                        sOut[row * 20 + n] = outacc[mt][dt][reg];
                    }
                }
            }
    }
    __syncthreads();   // BAR5: partials visible

    // ================= Phase 6: head0 combines + stores ========================
    if (head == 0) {
        float* ob = out + (size_t)b * (SEQL * DH);
#pragma unroll
        for (int mt = 0; mt < 4; ++mt)
#pragma unroll
            for (int dt = 0; dt < 2; ++dt) {
                int n = dt * 16 + c;
                if (n < 20) {
#pragma unroll
                    for (int reg = 0; reg < 4; ++reg) {
                        int row = rowbase + mt * 16 + qd * 4 + reg;
                        ob[row * 20 + n] = outacc[mt][dt][reg] + sOut[row * 20 + n];
                    }
                }
            }
    }
}

extern "C" void kernel_launch(void* const* d_in, const int* in_sizes, int n_in,
                              void* d_out, int out_size, void* d_ws, size_t ws_size,
                              hipStream_t stream) {
    const float* x  = (const float*)d_in[0];
    const float* y  = (const float*)d_in[1];
    const float* wq = (const float*)d_in[2];
    const float* wk = (const float*)d_in[3];
    const float* wv = (const float*)d_in[4];
    const float* wh = (const float*)d_in[5];
    float* out = (float*)d_out;

    set_attn_v16<<<dim3(NSET * NSET), dim3(512), 0, stream>>>(x, y, wq, wk, wv, wh, out);
}

// Round 13
// 125.263 us; speedup vs baseline: 1.1762x; 1.0262x over previous
//
#include <hip/hip_runtime.h>
#include <stdint.h>

// set attention: N=32, L=256, D=20, H=2, Dh=20, fp32 I/O.
// Out batch b: Q from x[b], K/V from y[(b&31)*32 + (b>>5)].
// R17: v16 (57us, passed) + v14's pack cut, now hazard-safe.
//   v16 closed the NaN mystery: inline-asm v_exp_f32 TRANS hazard; builtin
//   exp2f gets compiler spacing. v14's C-nudge+trunc-pack math was sound:
//   C = log2(1+2^-9) on QK^T MFMA pre-scales exp2 by (1+2^-9); bare v_perm
//   truncation then rounds centered; common factor cancels num/denom
//   (ones-column sums same truncated P). Combo 13 -> 9 issue slots.
// Everything else v16-proven verbatim.

#define NSET 32
#define SEQL 256
#define DM   20
#define NH   2
#define DH   20

typedef __attribute__((ext_vector_type(8))) short short8;
typedef __attribute__((ext_vector_type(4))) short short4v;
typedef __attribute__((ext_vector_type(4))) float f32x4;

#define MFMA32(a, b, c) __builtin_amdgcn_mfma_f32_16x16x32_bf16((a), (b), (c), 0, 0, 0)

#if __has_builtin(__builtin_amdgcn_mfma_f32_16x16x16bf16_1k)
#define MFMA16(a, b, c) __builtin_amdgcn_mfma_f32_16x16x16bf16_1k((a), (b), (c), 0, 0, 0)
#elif __has_builtin(__builtin_amdgcn_mfma_f32_16x16x16_bf16)
#define MFMA16(a, b, c) __builtin_amdgcn_mfma_f32_16x16x16_bf16((a), (b), (c), 0, 0, 0)
#else
static __device__ __forceinline__ f32x4 MFMA16(short4v a, short4v b, f32x4 c) {
    asm volatile("s_nop 1\n\tv_mfma_f32_16x16x16_bf16 %0, %1, %2, %0\n\ts_nop 7"
                 : "+v"(c) : "v"(a), "v"(b));
    return c;
}
#endif

#if __has_builtin(__builtin_amdgcn_exp2f)
#define EXP_BUILTIN 1
__device__ __forceinline__ float fexp2(float x) { return __builtin_amdgcn_exp2f(x); }
#else
#define EXP_BUILTIN 0
__device__ __forceinline__ float fexp2(float x) {
    float r;
    asm("v_exp_f32 %0, %1" : "=v"(r) : "v"(x));
    return r;
}
#endif

// fp32 -> bf16 bits, round-half-up (differs from RNE only on exact ties)
__device__ __forceinline__ uint32_t bfhu(float f) {
    return (__float_as_uint(f) + 0x8000u) >> 16;
}
// two fp32 -> packed {bf16(hi),bf16(lo)} with round-half-up: 2 add + 1 perm
__device__ __forceinline__ uint32_t packbf(float hi, float lo) {
    return __builtin_amdgcn_perm(__float_as_uint(hi) + 0x8000u,
                                 __float_as_uint(lo) + 0x8000u, 0x07060302u);
}
// two fp32 -> packed bf16 by TRUNCATION (inputs pre-nudged via MFMA C): 1 perm
__device__ __forceinline__ uint32_t pktrunc(float hi, float lo) {
    return __builtin_amdgcn_perm(__float_as_uint(hi), __float_as_uint(lo),
                                 0x07060302u);
}

// predicated A/B-frag load from row-major [rows][20] bf16 region (two b64 reads)
__device__ __forceinline__ short8 ldsA20(const short* base, int row, int qd) {
    uint2 lo = make_uint2(0u, 0u), hi = make_uint2(0u, 0u);
    const short* p = base + row * 20 + qd * 8;
    if (qd < 2) { lo = *(const uint2*)p; hi = *(const uint2*)(p + 4); }
    else if (qd == 2) { lo = *(const uint2*)p; }
    short8 f;
    *(uint2*)&f = lo;
    *(((uint2*)&f) + 1) = hi;
    return f;
}

// XOR-swizzled short-index into a head's sVt [21][256]: flips s bits 2..4 by d&7
__device__ __forceinline__ int vtoff(int d, int s) {
    return d * 256 + (s ^ ((d & 7) << 2));
}

// global fp32 row (20 floats, 16B-aligned) -> bf16 frag for k-quad qd (v8-proven)
__device__ __forceinline__ short8 gfrag(const float* rowp, int qd) {
    short8 f = {0, 0, 0, 0, 0, 0, 0, 0};
    if (qd < 2) {
        float4 a = *(const float4*)(rowp + qd * 8);
        float4 b = *(const float4*)(rowp + qd * 8 + 4);
        *(uint2*)&f = make_uint2(packbf(a.y, a.x), packbf(a.w, a.z));
        *(((uint2*)&f) + 1) = make_uint2(packbf(b.y, b.x), packbf(b.w, b.z));
    } else if (qd == 2) {
        float4 a = *(const float4*)(rowp + 16);
        *(uint2*)&f = make_uint2(packbf(a.y, a.x), packbf(a.w, a.z));
    }
    return f;
}

// weight B/A-frag gather, stride 40 floats (WQ/WK/WV: [20][40]).
__device__ __forceinline__ short8 gatherW40(const float* colp, int qd, bool act) {
    uint32_t u0 = 0u, u1 = 0u, u2 = 0u, u3 = 0u;
    if (act && qd < 3) {
        const float* p = colp + qd * 8 * 40;
        u0 = packbf(p[40], p[0]);
        u1 = packbf(p[120], p[80]);
        if (qd < 2) {
            u2 = packbf(p[200], p[160]);
            u3 = packbf(p[280], p[240]);
        }
    }
    short8 f;
    *(uint2*)&f = make_uint2(u0, u1);
    *(((uint2*)&f) + 1) = make_uint2(u2, u3);
    return f;
}

// same, stride 20 floats (WH: [40][20])
__device__ __forceinline__ short8 gatherW20(const float* colp, int qd, bool act) {
    uint32_t u0 = 0u, u1 = 0u, u2 = 0u, u3 = 0u;
    if (act && qd < 3) {
        const float* p = colp + qd * 8 * 20;
        u0 = packbf(p[20], p[0]);
        u1 = packbf(p[60], p[40]);
        if (qd < 2) {
            u2 = packbf(p[100], p[80]);
            u3 = packbf(p[140], p[120]);
        }
    }
    short8 f;
    *(uint2*)&f = make_uint2(u0, u1);
    *(((uint2*)&f) + 1) = make_uint2(u2, u3);
    return f;
}

// LDS layout (41,984 B total):
//   [     0, 20480)  sKb : bf16 K, [2 heads][256 rows][20]
//                          (overlay: per-wave O scratch after BAR2; f32 sOut after BAR4)
//   [ 20480, 41984)  sVtb: bf16 V^T, [2 heads][21 d][256 s] XOR-swizzled
//                          (d=20 row = 1.0 -> MFMA computes softmax denominator)
#define SMEM_BYTES 41984

__global__ __launch_bounds__(512, 4) void set_attn_v17(
    const float* __restrict__ x, const float* __restrict__ y,
    const float* __restrict__ wq, const float* __restrict__ wk,
    const float* __restrict__ wv, const float* __restrict__ wh,
    float* __restrict__ out)
{
    __shared__ __align__(16) char smem[SMEM_BYTES];
    short* sKb  = (short*)smem;
    short* sVtb = (short*)(smem + 20480);
    float* sOut = (float*)smem;            // overlay on sKb: [256][20] f32, epilogue only

    const int tid     = threadIdx.x;
    const int lane    = tid & 63;
    const int w       = tid >> 6;          // 0..7
    const int c       = lane & 15;
    const int qd      = lane >> 4;
    const int head    = w >> 2;            // 0 or 1
    const int rowbase = (w & 3) * 64;      // this wave's 64 rows
    const int b       = blockIdx.x;
    const int bi      = b >> 5, bj = b & 31;

    short* sK  = sKb + head * (SEQL * 20);
    short* sVt = sVtb + head * (21 * 256);
    short* myO = sKb + w * (64 * 20);      // O scratch overlay, live BAR2..BAR4

    // ones-row d=20 (denominator column); each wave covers its 64 s values
    sVt[vtoff(20, rowbase + lane)] = (short)0x3F80;

    const float QS = 0.22360679774997896f * 1.4426950408889634f;  // scale * log2(e)

    // ================= Phase 1: projections (own head, own 64 rows) ============
    short8 xf[4];
#pragma unroll
    for (int mt = 0; mt < 4; ++mt)
        xf[mt] = gfrag(x + ((size_t)b * SEQL + rowbase + mt * 16 + c) * DM, qd);

    // Qt A-frags: wqA0 lane(c,qd): WQ[k=8qd+j][h*20+c]; wqA1: col 16+c (c<4)
    short8 wqA0 = gatherW40(wq + head * 20 + c, qd, true);
    short8 wqA1 = gatherW40(wq + head * 20 + 16 + c, qd, c < 4);

    // K/V projection B-frags
    short8 wkf[2], wvf[2];
#pragma unroll
    for (int dt = 0; dt < 2; ++dt) {
        int n = dt * 16 + c;
        wkf[dt] = gatherW40(wk + head * 20 + n, qd, n < 20);
        wvf[dt] = gatherW40(wv + head * 20 + n, qd, n < 20);
    }

    // bpermute lane indices for qb assembly (bytes)
    const int i01 = (c + ((qd & 1) << 5)) << 2;        // qd0->c,   qd1->c+32
    const int i23 = (c + 16 + ((qd & 1) << 5)) << 2;   // qd0->c+16, qd1->c+48
    const int iB  = c << 2;                            // qd2 -> lane (c,0)

    short8 qb[4];
#pragma unroll
    for (int mt = 0; mt < 4; ++mt) {
        int rb = rowbase + mt * 16;        // local row in [0,256)
        short8 yf = gfrag(y + ((size_t)(bj * NSET + bi) * SEQL + rb + c) * DM, qd);
#pragma unroll
        for (int dt = 0; dt < 2; ++dt) {
            f32x4 z = {0.f, 0.f, 0.f, 0.f};
            f32x4 kres = MFMA32(yf, wkf[dt], z);
            f32x4 vres = MFMA32(yf, wvf[dt], z);
            int n = dt * 16 + c;
            if (n < 20) {
#pragma unroll
                for (int reg = 0; reg < 4; ++reg)
                    sK[(rb + qd * 4 + reg) * 20 + n] = (short)bfhu(kres[reg]);
                uint2 pv = make_uint2(packbf(vres[1], vres[0]),
                                      packbf(vres[3], vres[2]));
                *(uint2*)(sVt + vtoff(n, rb + qd * 4)) = pv;
            }
        }
        // --- Q^T projection + in-register transpose to qb[mt] (v11-proven) ---
        {
            f32x4 z = {0.f, 0.f, 0.f, 0.f};
            f32x4 ra = MFMA32(wqA0, xf[mt], z);   // lane(c,qd): Q[c][4qd+reg]
            f32x4 rb2 = MFMA32(wqA1, xf[mt], z);  // qd==0: Q[c][16+reg], else 0
            uint32_t dwA0 = packbf(ra[1] * QS, ra[0] * QS);
            uint32_t dwA1 = packbf(ra[3] * QS, ra[2] * QS);
            uint32_t dwB0 = packbf(rb2[1] * QS, rb2[0] * QS);
            uint32_t dwB1 = packbf(rb2[3] * QS, rb2[2] * QS);
            uint32_t t0a = (uint32_t)__builtin_amdgcn_ds_bpermute(i01, (int)dwA0);
            uint32_t t1a = (uint32_t)__builtin_amdgcn_ds_bpermute(i01, (int)dwA1);
            uint32_t t0b = (uint32_t)__builtin_amdgcn_ds_bpermute(iB, (int)dwB0);
            uint32_t t1b = (uint32_t)__builtin_amdgcn_ds_bpermute(iB, (int)dwB1);
            uint32_t t2  = (uint32_t)__builtin_amdgcn_ds_bpermute(i23, (int)dwA0);
            uint32_t t3  = (uint32_t)__builtin_amdgcn_ds_bpermute(i23, (int)dwA1);
            uint32_t q0 = qd < 2 ? t0a : (qd == 2 ? t0b : 0u);
            uint32_t q1 = qd < 2 ? t1a : (qd == 2 ? t1b : 0u);
            uint32_t q2 = qd < 2 ? t2 : 0u;
            uint32_t q3 = qd < 2 ? t3 : 0u;
            short8 f;
            *(uint2*)&f = make_uint2(q0, q1);
            *(((uint2*)&f) + 1) = make_uint2(q2, q3);
            qb[mt] = f;   // lane(c,qd): Qs[row mt*16+c][d=8qd+j]
        }
    }
    __syncthreads();   // BAR1: sK/sVt (both heads, incl. ones-row) ready

    // ================= Phase 2: s0 loop (ONE head) =============================
    f32x4 oacc[4][2];
#pragma unroll
    for (int mt = 0; mt < 4; ++mt)
#pragma unroll
        for (int dt = 0; dt < 2; ++dt) oacc[mt][dt] = (f32x4){0.f, 0.f, 0.f, 0.f};

#if EXP_BUILTIN
    // round-nudge: exp2(v + CN) = exp2(v)*(1+2^-9); truncation pack then rounds
    // centered; common factor cancels num/denom (ones-column sums same P)
    const float CN = 0.0028151f;   // log2(1 + 2^-9)
    const f32x4 cnud = {CN, CN, CN, CN};
#else
    const f32x4 cnud = {0.f, 0.f, 0.f, 0.f};
#endif

    for (int s0 = 0; s0 < SEQL; s0 += 32) {
        short8 kf0 = ldsA20(sK, s0 + c, qd);
        short8 kf1 = ldsA20(sK, s0 + 16 + c, qd);
        short4v vb[2][2];
#pragma unroll
        for (int dt = 0; dt < 2; ++dt) {
            int d = dt * 16 + c;
#pragma unroll
            for (int st = 0; st < 2; ++st) {
                uint2 u = make_uint2(0u, 0u);
                if (d < 21)   // d==20 loads the ones-row -> denom column
                    u = *(const uint2*)(sVt + vtoff(d, s0 + st * 16 + qd * 4));
                short4v t; *(uint2*)&t = u;
                vb[st][dt] = t;
            }
        }
#pragma unroll
        for (int mt = 0; mt < 4; ++mt) {
#pragma unroll
            for (int st = 0; st < 2; ++st) {
                f32x4 sacc = MFMA32((st == 0 ? kf0 : kf1), qb[mt], cnud);
#if EXP_BUILTIN
                float p0 = fexp2(sacc[0]);
                float p1 = fexp2(sacc[1]);
                float p2 = fexp2(sacc[2]);
                float p3 = fexp2(sacc[3]);
                short4v pf;
                *(uint2*)&pf = make_uint2(pktrunc(p1, p0), pktrunc(p3, p2));
#else
                // fallback: v13's exact masked inline-asm form (hazard-spaced)
                float p0 = (sacc[0] != 0.f) ? fexp2(sacc[0]) : 0.f;
                float p1 = (sacc[1] != 0.f) ? fexp2(sacc[1]) : 0.f;
                float p2 = (sacc[2] != 0.f) ? fexp2(sacc[2]) : 0.f;
                float p3 = (sacc[3] != 0.f) ? fexp2(sacc[3]) : 0.f;
                short4v pf;
                *(uint2*)&pf = make_uint2(packbf(p1, p0), packbf(p3, p2));
#endif
                oacc[mt][0] = MFMA16(pf, vb[st][0], oacc[mt][0]);
                oacc[mt][1] = MFMA16(pf, vb[st][1], oacc[mt][1]);
            }
        }
    }
    __syncthreads();   // BAR2: ALL s0-loop reads of sK/sVt done -> overlay safe

    // ================= Phase 3: normalize O into sK-overlay scratch ============
    // denominator of row mt*16+qd*4+reg = oacc[mt][1][reg] at lane qd*16+4 (d=20)
    short8 whf[2];
#pragma unroll
    for (int dt = 0; dt < 2; ++dt) {
        int n = dt * 16 + c;
        whf[dt] = gatherW20(wh + head * 20 * 20 + n, qd, n < 20);
    }
    const int dsrc = (lane & 48) + 4;   // lane qd*16+4 of own qd group
#pragma unroll
    for (int mt = 0; mt < 4; ++mt) {
        float inv[4];
#pragma unroll
        for (int reg = 0; reg < 4; ++reg)
            inv[reg] = 1.f / (__shfl(oacc[mt][1][reg], dsrc, 64) + 1e-10f);
#pragma unroll
        for (int dt = 0; dt < 2; ++dt) {
            int n = dt * 16 + c;
            if (n < 20) {
#pragma unroll
                for (int reg = 0; reg < 4; ++reg)
                    myO[(mt * 16 + qd * 4 + reg) * 20 + n] =
                        (short)bfhu(oacc[mt][dt][reg] * inv[reg]);
            }
        }
    }
    __syncthreads();   // BAR3: O writes visible before transposed read

    // ================= Phase 4: out-projection partial (own head) ==============
    f32x4 outacc[4][2];
#pragma unroll
    for (int mt = 0; mt < 4; ++mt) {
        short8 of = ldsA20(myO, mt * 16 + c, qd);
        f32x4 z = {0.f, 0.f, 0.f, 0.f};
        outacc[mt][0] = MFMA32(of, whf[0], z);
        outacc[mt][1] = MFMA32(of, whf[1], z);
    }
    __syncthreads();   // BAR4: all myO reads retired -> f32 sOut overlay safe

    // ================= Phase 5: head1 writes f32 partials to sOut ==============
    if (head == 1) {
#pragma unroll
        for (int mt = 0; mt < 4; ++mt)
#pragma unroll
            for (int dt = 0; dt < 2; ++dt) {
                int n = dt * 16 + c;
                if (n < 20) {
#pragma unroll
                    for (int reg = 0; reg < 4; ++reg) {
                        int row = rowbase + mt * 16 + qd * 4 + reg;
                        sOut[row * 20 + n] = outacc[mt][dt][reg];
                    }
                }
            }
    }
    __syncthreads();   // BAR5: partials visible

    // ================= Phase 6: head0 combines + stores ========================
    if (head == 0) {
        float* ob = out + (size_t)b * (SEQL * DH);
#pragma unroll
        for (int mt = 0; mt < 4; ++mt)
#pragma unroll
            for (int dt = 0; dt < 2; ++dt) {
                int n = dt * 16 + c;
                if (n < 20) {
#pragma unroll
                    for (int reg = 0; reg < 4; ++reg) {
                        int row = rowbase + mt * 16 + qd * 4 + reg;
                        ob[row * 20 + n] = outacc[mt][dt][reg] + sOut[row * 20 + n];
                    }
                }
            }
    }
}

extern "C" void kernel_launch(void* const* d_in, const int* in_sizes, int n_in,
                              void* d_out, int out_size, void* d_ws, size_t ws_size,
                              hipStream_t stream) {
    const float* x  = (const float*)d_in[0];
    const float* y  = (const float*)d_in[1];
    const float* wq = (const float*)d_in[2];
    const float* wk = (const float*)d_in[3];
    const float* wv = (const float*)d_in[4];
    const float* wh = (const float*)d_in[5];
    float* out = (float*)d_out;

    set_attn_v17<<<dim3(NSET * NSET), dim3(512), 0, stream>>>(x, y, wq, wk, wv, wh, out);
}